// Round 1
// baseline (5818.946 us; speedup 1.0000x reference)
//
#include <hip/hip_runtime.h>

#define HD 128   // hidden dim

// ---- degree counting ----
__global__ __launch_bounds__(256) void count_deg(const int* __restrict__ src,
                                                 const int* __restrict__ dst,
                                                 float* __restrict__ outdeg,
                                                 float* __restrict__ indeg, int E) {
    int e = blockIdx.x * 256 + threadIdx.x;
    if (e < E) {
        atomicAdd(&outdeg[src[e]], 1.0f);
        atomicAdd(&indeg[dst[e]], 1.0f);
    }
}

// deg -> rsqrt(max(deg,1)) in place, both arrays contiguous (length 2N)
__global__ __launch_bounds__(256) void deg_to_norm(float* __restrict__ d, int n2) {
    int i = blockIdx.x * 256 + threadIdx.x;
    if (i < n2) {
        float v = d[i];
        d[i] = rsqrtf(v > 1.0f ? v : 1.0f);
    }
}

// ---- h = (x * norm_src[:,None]) @ W ----
// Block: 256 threads -> 8 rows x (32 threads x float4 cols). W staged in LDS (64KB).
__global__ __launch_bounds__(256) void gemm_norm(const float* __restrict__ x,
                                                 const float* __restrict__ norm,
                                                 const float* __restrict__ W,
                                                 float* __restrict__ h, int n) {
    __shared__ float Ws[HD * HD];     // 64 KB
    __shared__ float xs[8][HD];       // 4 KB
    const float4* W4 = (const float4*)W;
    float4* Ws4 = (float4*)Ws;
#pragma unroll
    for (int i = 0; i < 16; ++i)
        Ws4[threadIdx.x + 256 * i] = W4[threadIdx.x + 256 * i];

    const int r   = threadIdx.x >> 5;   // 0..7   row within tile
    const int c4  = threadIdx.x & 31;   // 0..31  float4 column
    const int row = blockIdx.x * 8 + r;

    float4 xv = make_float4(0.f, 0.f, 0.f, 0.f);
    float nrm = 0.f;
    if (row < n) {
        nrm = norm[row];
        xv = ((const float4*)x)[(size_t)row * 32 + c4];
    }
    xv.x *= nrm; xv.y *= nrm; xv.z *= nrm; xv.w *= nrm;
    ((float4*)xs[r])[c4] = xv;
    __syncthreads();

    float4 acc = make_float4(0.f, 0.f, 0.f, 0.f);
#pragma unroll 8
    for (int k = 0; k < HD; ++k) {
        float xk = xs[r][k];            // broadcast within 32-thread group
        float4 wv = Ws4[k * 32 + c4];   // ds_read_b128, conflict-free
        acc.x = fmaf(xk, wv.x, acc.x);
        acc.y = fmaf(xk, wv.y, acc.y);
        acc.z = fmaf(xk, wv.z, acc.z);
        acc.w = fmaf(xk, wv.w, acc.w);
    }
    if (row < n)
        ((float4*)h)[(size_t)row * 32 + c4] = acc;
}

// ---- agg[dst] += h[src]  (per (edge, float4-lane) thread) ----
__global__ __launch_bounds__(256) void scatter_add(const float* __restrict__ h,
                                                   const int* __restrict__ src,
                                                   const int* __restrict__ dst,
                                                   float* __restrict__ agg,
                                                   unsigned int total) {
    unsigned int t = blockIdx.x * 256u + threadIdx.x;
    if (t >= total) return;
    int e  = (int)(t >> 5);
    int c4 = (int)(t & 31u);
    int s = src[e], d = dst[e];
    float4 v = ((const float4*)h)[(size_t)s * 32 + c4];
    float* a = agg + (size_t)d * HD + c4 * 4;
    atomicAdd(a + 0, v.x);
    atomicAdd(a + 1, v.y);
    atomicAdd(a + 2, v.z);
    atomicAdd(a + 3, v.w);
}

// ---- out = relu(agg * norm_dst[:,None] + b) ----
__global__ __launch_bounds__(256) void finish(const float* __restrict__ agg,
                                              const float* __restrict__ norm,
                                              const float* __restrict__ b,
                                              float* __restrict__ out,
                                              unsigned int total) {
    unsigned int t = blockIdx.x * 256u + threadIdx.x;
    if (t >= total) return;
    int row = (int)(t >> 5);
    int c4  = (int)(t & 31u);
    float nd = norm[row];
    float4 v  = ((const float4*)agg)[t];
    float4 bb = ((const float4*)b)[c4];
    float4 o;
    o.x = fmaxf(fmaf(v.x, nd, bb.x), 0.f);
    o.y = fmaxf(fmaf(v.y, nd, bb.y), 0.f);
    o.z = fmaxf(fmaf(v.z, nd, bb.z), 0.f);
    o.w = fmaxf(fmaf(v.w, nd, bb.w), 0.f);
    ((float4*)out)[t] = o;
}

extern "C" void kernel_launch(void* const* d_in, const int* in_sizes, int n_in,
                              void* d_out, int out_size, void* d_ws, size_t ws_size,
                              hipStream_t stream) {
    const float* x   = (const float*)d_in[0];
    const float* W1  = (const float*)d_in[1];
    const float* b1  = (const float*)d_in[2];
    const float* W2  = (const float*)d_in[3];
    const float* b2  = (const float*)d_in[4];
    const int*   src = (const int*)d_in[5];
    const int*   dst = (const int*)d_in[6];

    const int N = in_sizes[0] / HD;
    const int E = in_sizes[5];
    float* out = (float*)d_out;

    // workspace layout
    float* outdeg = (float*)d_ws;                  // N  (becomes norm_src)
    float* indeg  = outdeg + N;                    // N  (becomes norm_dst)
    float* h      = indeg + N;                     // N*HD
    float* agg    = h + (size_t)N * HD;            // N*HD

    const unsigned int rowTot = (unsigned int)N * 32u;       // float4 slots per feature map
    const unsigned int edgeTot = (unsigned int)E * 32u;

    // degrees -> norms
    hipMemsetAsync(outdeg, 0, (size_t)2 * N * sizeof(float), stream);
    count_deg<<<(E + 255) / 256, 256, 0, stream>>>(src, dst, outdeg, indeg, E);
    deg_to_norm<<<(2 * N + 255) / 256, 256, 0, stream>>>(outdeg, 2 * N);

    // ---- layer 1 ----
    gemm_norm<<<(N + 7) / 8, 256, 0, stream>>>(x, outdeg, W1, h, N);
    hipMemsetAsync(agg, 0, (size_t)N * HD * sizeof(float), stream);
    scatter_add<<<(edgeTot + 255) / 256, 256, 0, stream>>>(h, src, dst, agg, edgeTot);
    finish<<<(rowTot + 255) / 256, 256, 0, stream>>>(agg, indeg, b1, out, rowTot);

    // ---- layer 2 ----
    gemm_norm<<<(N + 7) / 8, 256, 0, stream>>>(out, outdeg, W2, h, N);
    hipMemsetAsync(agg, 0, (size_t)N * HD * sizeof(float), stream);
    scatter_add<<<(edgeTot + 255) / 256, 256, 0, stream>>>(h, src, dst, agg, edgeTot);
    finish<<<(rowTot + 255) / 256, 256, 0, stream>>>(agg, indeg, b2, out, rowTot);
}

// Round 2
// 786.339 us; speedup vs baseline: 7.4000x; 7.4000x over previous
//
#include <hip/hip_runtime.h>

#define HD 128   // hidden dim

// ---- degree counting: float out-degree (for norm_src) + int in-degree (for CSR) ----
__global__ __launch_bounds__(256) void count_deg(const int* __restrict__ src,
                                                 const int* __restrict__ dst,
                                                 float* __restrict__ outdeg,
                                                 unsigned int* __restrict__ cnt, int E) {
    int e = blockIdx.x * 256 + threadIdx.x;
    if (e < E) {
        atomicAdd(&outdeg[src[e]], 1.0f);
        atomicAdd(&cnt[dst[e]], 1u);
    }
}

// norm_src (in place over outdeg), norm_dst from int counts
__global__ __launch_bounds__(256) void make_norms(float* __restrict__ outdeg,
                                                  const unsigned int* __restrict__ cnt,
                                                  float* __restrict__ norm_dst, int n) {
    int i = blockIdx.x * 256 + threadIdx.x;
    if (i < n) {
        float od = outdeg[i];
        outdeg[i] = rsqrtf(od > 1.0f ? od : 1.0f);
        float id = (float)cnt[i];
        norm_dst[i] = rsqrtf(id > 1.0f ? id : 1.0f);
    }
}

// ---- exclusive scan of cnt -> offsets (3 phases) ----
__global__ __launch_bounds__(256) void scan_a(const unsigned int* __restrict__ cnt,
                                              unsigned int* __restrict__ excl,
                                              unsigned int* __restrict__ bsum, int n) {
    int i = blockIdx.x * 256 + threadIdx.x;
    unsigned int v = (i < n) ? cnt[i] : 0u;
    unsigned int x = v;
#pragma unroll
    for (int d = 1; d < 64; d <<= 1) {
        unsigned int y = __shfl_up(x, d, 64);
        if ((threadIdx.x & 63) >= d) x += y;
    }
    __shared__ unsigned int wsum[4];
    if ((threadIdx.x & 63) == 63) wsum[threadIdx.x >> 6] = x;
    __syncthreads();
    unsigned int woff = 0;
    for (int w = 0; w < (int)(threadIdx.x >> 6); ++w) woff += wsum[w];
    unsigned int incl = x + woff;
    if (i < n) excl[i] = incl - v;
    if (threadIdx.x == 255) bsum[blockIdx.x] = incl;
}

__global__ __launch_bounds__(1024) void scan_b(const unsigned int* __restrict__ bsum,
                                               unsigned int* __restrict__ boff, int nb) {
    int t = threadIdx.x;
    unsigned int v = (t < nb) ? bsum[t] : 0u;
    unsigned int x = v;
#pragma unroll
    for (int d = 1; d < 64; d <<= 1) {
        unsigned int y = __shfl_up(x, d, 64);
        if ((t & 63) >= d) x += y;
    }
    __shared__ unsigned int wsum[16];
    if ((t & 63) == 63) wsum[t >> 6] = x;
    __syncthreads();
    unsigned int woff = 0;
    for (int w = 0; w < (t >> 6); ++w) woff += wsum[w];
    unsigned int incl = x + woff;
    if (t < nb) boff[t] = incl - v;
}

__global__ __launch_bounds__(256) void scan_c(unsigned int* __restrict__ excl,
                                              const unsigned int* __restrict__ boff, int n) {
    int i = blockIdx.x * 256 + threadIdx.x;
    if (i < n) excl[i] += boff[blockIdx.x];
}

// ---- scatter edge src-ids into dst-sorted order ----
__global__ __launch_bounds__(256) void fill_csr(const int* __restrict__ src,
                                                const int* __restrict__ dst,
                                                const unsigned int* __restrict__ offsets,
                                                unsigned int* __restrict__ cursor,
                                                int* __restrict__ sorted_src, int E) {
    int e = blockIdx.x * 256 + threadIdx.x;
    if (e < E) {
        int d = dst[e];
        unsigned int pos = offsets[d] + atomicAdd(&cursor[d], 1u);
        sorted_src[pos] = src[e];
    }
}

// ---- h = (x * norm_src[:,None]) @ W ----
__global__ __launch_bounds__(256) void gemm_norm(const float* __restrict__ x,
                                                 const float* __restrict__ norm,
                                                 const float* __restrict__ W,
                                                 float* __restrict__ h, int n) {
    __shared__ float Ws[HD * HD];     // 64 KB
    __shared__ float xs[8][HD];       // 4 KB
    const float4* W4 = (const float4*)W;
    float4* Ws4 = (float4*)Ws;
#pragma unroll
    for (int i = 0; i < 16; ++i)
        Ws4[threadIdx.x + 256 * i] = W4[threadIdx.x + 256 * i];

    const int r   = threadIdx.x >> 5;
    const int c4  = threadIdx.x & 31;
    const int row = blockIdx.x * 8 + r;

    float4 xv = make_float4(0.f, 0.f, 0.f, 0.f);
    float nrm = 0.f;
    if (row < n) {
        nrm = norm[row];
        xv = ((const float4*)x)[(size_t)row * 32 + c4];
    }
    xv.x *= nrm; xv.y *= nrm; xv.z *= nrm; xv.w *= nrm;
    ((float4*)xs[r])[c4] = xv;
    __syncthreads();

    float4 acc = make_float4(0.f, 0.f, 0.f, 0.f);
#pragma unroll 8
    for (int k = 0; k < HD; ++k) {
        float xk = xs[r][k];
        float4 wv = Ws4[k * 32 + c4];
        acc.x = fmaf(xk, wv.x, acc.x);
        acc.y = fmaf(xk, wv.y, acc.y);
        acc.z = fmaf(xk, wv.z, acc.z);
        acc.w = fmaf(xk, wv.w, acc.w);
    }
    if (row < n)
        ((float4*)h)[(size_t)row * 32 + c4] = acc;
}

// ---- fused gather-aggregate + norm + bias + relu: one wave per dst node ----
__global__ __launch_bounds__(256) void aggregate(const float* __restrict__ h,
                                                 const int* __restrict__ sorted_src,
                                                 const unsigned int* __restrict__ offsets,
                                                 const unsigned int* __restrict__ cnt,
                                                 const float* __restrict__ norm_dst,
                                                 const float* __restrict__ bias,
                                                 float* __restrict__ out, int n) {
    int node = blockIdx.x * 4 + (int)(threadIdx.x >> 6);
    if (node >= n) return;
    int lane = threadIdx.x & 63;

    unsigned int start = offsets[node];
    unsigned int deg   = cnt[node];

    const float2* h2 = (const float2*)h;
    float ax = 0.f, ay = 0.f;
    for (unsigned int i = 0; i < deg; ++i) {
        int s = sorted_src[start + i];          // wave-uniform broadcast load
        float2 v = h2[(size_t)s * 64 + lane];   // 512B coalesced per row
        ax += v.x; ay += v.y;
    }
    float nd = norm_dst[node];
    float2 bb = ((const float2*)bias)[lane];
    float2 o;
    o.x = fmaxf(fmaf(ax, nd, bb.x), 0.f);
    o.y = fmaxf(fmaf(ay, nd, bb.y), 0.f);
    ((float2*)out)[(size_t)node * 64 + lane] = o;
}

extern "C" void kernel_launch(void* const* d_in, const int* in_sizes, int n_in,
                              void* d_out, int out_size, void* d_ws, size_t ws_size,
                              hipStream_t stream) {
    const float* x   = (const float*)d_in[0];
    const float* W1  = (const float*)d_in[1];
    const float* b1  = (const float*)d_in[2];
    const float* W2  = (const float*)d_in[3];
    const float* b2  = (const float*)d_in[4];
    const int*   src = (const int*)d_in[5];
    const int*   dst = (const int*)d_in[6];

    const int N = in_sizes[0] / HD;
    const int E = in_sizes[5];
    float* out = (float*)d_out;

    const int nbA = (N + 255) / 256;   // scan phase-A blocks (<=1024)

    // workspace layout (zero-needed region contiguous: outdeg, cnt, cursor)
    float*        outdeg  = (float*)d_ws;                 // N   -> norm_src
    unsigned int* cnt     = (unsigned int*)(outdeg + N);  // N
    unsigned int* cursor  = cnt + N;                      // N
    float*        normd   = (float*)(cursor + N);         // N
    unsigned int* offsets = (unsigned int*)(normd + N);   // N
    unsigned int* bsum    = offsets + N;                  // 1024
    unsigned int* boff    = bsum + 1024;                  // 1024
    int*          sorted  = (int*)(boff + 1024);          // E
    float*        h       = (float*)(sorted + E);         // N*HD

    // ---- CSR build (shared by both layers) ----
    hipMemsetAsync(outdeg, 0, (size_t)3 * N * 4, stream);
    count_deg<<<(E + 255) / 256, 256, 0, stream>>>(src, dst, outdeg, cnt, E);
    make_norms<<<nbA, 256, 0, stream>>>(outdeg, cnt, normd, N);
    scan_a<<<nbA, 256, 0, stream>>>(cnt, offsets, bsum, N);
    scan_b<<<1, 1024, 0, stream>>>(bsum, boff, nbA);
    scan_c<<<nbA, 256, 0, stream>>>(offsets, boff, N);
    fill_csr<<<(E + 255) / 256, 256, 0, stream>>>(src, dst, offsets, cursor, sorted, E);

    // ---- layer 1 ----
    gemm_norm<<<(N + 7) / 8, 256, 0, stream>>>(x, outdeg, W1, h, N);
    aggregate<<<(N + 3) / 4, 256, 0, stream>>>(h, sorted, offsets, cnt, normd, b1, out, N);

    // ---- layer 2 ----
    gemm_norm<<<(N + 7) / 8, 256, 0, stream>>>(out, outdeg, W2, h, N);
    aggregate<<<(N + 3) / 4, 256, 0, stream>>>(h, sorted, offsets, cnt, normd, b2, out, N);
}

// Round 3
// 505.782 us; speedup vs baseline: 11.5049x; 1.5547x over previous
//
#include <hip/hip_runtime.h>
#include <hip/hip_fp16.h>

#define HD 128   // hidden dim

// ---- degree counting: float out-degree (for norm_src) + int in-degree (for CSR) ----
__global__ __launch_bounds__(256) void count_deg(const int* __restrict__ src,
                                                 const int* __restrict__ dst,
                                                 float* __restrict__ outdeg,
                                                 unsigned int* __restrict__ cnt, int E) {
    int e = blockIdx.x * 256 + threadIdx.x;
    if (e < E) {
        atomicAdd(&outdeg[src[e]], 1.0f);
        atomicAdd(&cnt[dst[e]], 1u);
    }
}

__global__ __launch_bounds__(256) void make_norms(float* __restrict__ outdeg,
                                                  const unsigned int* __restrict__ cnt,
                                                  float* __restrict__ norm_dst, int n) {
    int i = blockIdx.x * 256 + threadIdx.x;
    if (i < n) {
        float od = outdeg[i];
        outdeg[i] = rsqrtf(od > 1.0f ? od : 1.0f);
        float id = (float)cnt[i];
        norm_dst[i] = rsqrtf(id > 1.0f ? id : 1.0f);
    }
}

// ---- exclusive scan of cnt -> offsets (3 phases) ----
__global__ __launch_bounds__(256) void scan_a(const unsigned int* __restrict__ cnt,
                                              unsigned int* __restrict__ excl,
                                              unsigned int* __restrict__ bsum, int n) {
    int i = blockIdx.x * 256 + threadIdx.x;
    unsigned int v = (i < n) ? cnt[i] : 0u;
    unsigned int x = v;
#pragma unroll
    for (int d = 1; d < 64; d <<= 1) {
        unsigned int y = __shfl_up(x, d, 64);
        if ((threadIdx.x & 63) >= d) x += y;
    }
    __shared__ unsigned int wsum[4];
    if ((threadIdx.x & 63) == 63) wsum[threadIdx.x >> 6] = x;
    __syncthreads();
    unsigned int woff = 0;
    for (int w = 0; w < (int)(threadIdx.x >> 6); ++w) woff += wsum[w];
    unsigned int incl = x + woff;
    if (i < n) excl[i] = incl - v;
    if (threadIdx.x == 255) bsum[blockIdx.x] = incl;
}

__global__ __launch_bounds__(1024) void scan_b(const unsigned int* __restrict__ bsum,
                                               unsigned int* __restrict__ boff, int nb) {
    int t = threadIdx.x;
    unsigned int v = (t < nb) ? bsum[t] : 0u;
    unsigned int x = v;
#pragma unroll
    for (int d = 1; d < 64; d <<= 1) {
        unsigned int y = __shfl_up(x, d, 64);
        if ((t & 63) >= d) x += y;
    }
    __shared__ unsigned int wsum[16];
    if ((t & 63) == 63) wsum[t >> 6] = x;
    __syncthreads();
    unsigned int woff = 0;
    for (int w = 0; w < (t >> 6); ++w) woff += wsum[w];
    unsigned int incl = x + woff;
    if (t < nb) boff[t] = incl - v;
}

__global__ __launch_bounds__(256) void scan_c(unsigned int* __restrict__ excl,
                                              const unsigned int* __restrict__ boff, int n) {
    int i = blockIdx.x * 256 + threadIdx.x;
    if (i < n) excl[i] += boff[blockIdx.x];
}

// ---- scatter edge src-ids into dst-sorted order ----
__global__ __launch_bounds__(256) void fill_csr(const int* __restrict__ src,
                                                const int* __restrict__ dst,
                                                const unsigned int* __restrict__ offsets,
                                                unsigned int* __restrict__ cursor,
                                                int* __restrict__ sorted_src, int E) {
    int e = blockIdx.x * 256 + threadIdx.x;
    if (e < E) {
        int d = dst[e];
        unsigned int pos = offsets[d] + atomicAdd(&cursor[d], 1u);
        sorted_src[pos] = src[e];
    }
}

// ---- h = (x * norm_src[:,None]) @ W, fp16 output ----
// 256 threads = 8 groups x 32 lanes; each group computes 4 rows; block tile = 32 rows.
__global__ __launch_bounds__(256) void gemm_norm(const float* __restrict__ x,
                                                 const float* __restrict__ norm,
                                                 const float* __restrict__ W,
                                                 __half* __restrict__ h, int n) {
    __shared__ float Ws[HD * HD];     // 64 KB
    __shared__ float xs[32][HD];      // 16 KB
    const float4* W4 = (const float4*)W;
    float4* Ws4 = (float4*)Ws;
#pragma unroll
    for (int i = 0; i < 16; ++i)
        Ws4[threadIdx.x + 256 * i] = W4[threadIdx.x + 256 * i];

    const int tid  = threadIdx.x;
    const int row0 = blockIdx.x * 32;

    // stage 32 rows of x, norm applied. thread -> row tid>>3, float4 cols (tid&7)*4..+3
    {
        int r  = tid >> 3;
        int c0 = (tid & 7) * 4;
        int row = row0 + r;
        float nrm = (row < n) ? norm[row] : 0.f;
        const float4* xr = (const float4*)(x + (size_t)row * HD);
        float4* xd = (float4*)xs[r];
#pragma unroll
        for (int j = 0; j < 4; ++j) {
            float4 v = (row < n) ? xr[c0 + j] : make_float4(0.f, 0.f, 0.f, 0.f);
            v.x *= nrm; v.y *= nrm; v.z *= nrm; v.w *= nrm;
            xd[c0 + j] = v;
        }
    }
    __syncthreads();

    const int g  = tid >> 5;    // group 0..7 -> rows g*4..g*4+3
    const int c4 = tid & 31;    // float4 output column

    float4 a0 = make_float4(0.f,0.f,0.f,0.f), a1 = a0, a2 = a0, a3 = a0;
#pragma unroll 4
    for (int k = 0; k < HD; ++k) {
        float4 wv = Ws4[k * 32 + c4];
        float x0 = xs[g * 4 + 0][k];
        float x1 = xs[g * 4 + 1][k];
        float x2 = xs[g * 4 + 2][k];
        float x3 = xs[g * 4 + 3][k];
        a0.x = fmaf(x0, wv.x, a0.x); a0.y = fmaf(x0, wv.y, a0.y);
        a0.z = fmaf(x0, wv.z, a0.z); a0.w = fmaf(x0, wv.w, a0.w);
        a1.x = fmaf(x1, wv.x, a1.x); a1.y = fmaf(x1, wv.y, a1.y);
        a1.z = fmaf(x1, wv.z, a1.z); a1.w = fmaf(x1, wv.w, a1.w);
        a2.x = fmaf(x2, wv.x, a2.x); a2.y = fmaf(x2, wv.y, a2.y);
        a2.z = fmaf(x2, wv.z, a2.z); a2.w = fmaf(x2, wv.w, a2.w);
        a3.x = fmaf(x3, wv.x, a3.x); a3.y = fmaf(x3, wv.y, a3.y);
        a3.z = fmaf(x3, wv.z, a3.z); a3.w = fmaf(x3, wv.w, a3.w);
    }

    // store 4 rows x float4 as fp16 (8B per row-store)
#pragma unroll
    for (int j = 0; j < 4; ++j) {
        int row = row0 + g * 4 + j;
        if (row >= n) break;
        float4 a = (j == 0) ? a0 : (j == 1) ? a1 : (j == 2) ? a2 : a3;
        __half2 lo = __floats2half2_rn(a.x, a.y);
        __half2 hi = __floats2half2_rn(a.z, a.w);
        uint2 pk;
        pk.x = *(unsigned int*)&lo;
        pk.y = *(unsigned int*)&hi;
        ((uint2*)(h + (size_t)row * HD))[c4] = pk;
    }
}

// ---- fused gather-aggregate + norm + bias + relu: one wave per dst node ----
__global__ __launch_bounds__(256) void aggregate(const __half* __restrict__ h,
                                                 const int* __restrict__ sorted_src,
                                                 const unsigned int* __restrict__ offsets,
                                                 const unsigned int* __restrict__ cnt,
                                                 const float* __restrict__ norm_dst,
                                                 const float* __restrict__ bias,
                                                 float* __restrict__ out, int n) {
    int node = blockIdx.x * 4 + (int)(threadIdx.x >> 6);
    if (node >= n) return;
    int lane = threadIdx.x & 63;

    unsigned int start = offsets[node];
    unsigned int deg   = cnt[node];
    const int* sp = sorted_src + start;
    const __half2* h2 = (const __half2*)h;   // lane owns cols 2*lane, 2*lane+1

    float ax = 0.f, ay = 0.f;
    unsigned int i = 0;
    for (; i + 4 <= deg; i += 4) {
        int s0 = sp[i], s1 = sp[i + 1], s2 = sp[i + 2], s3 = sp[i + 3];
        float2 v0 = __half22float2(h2[(size_t)s0 * 64 + lane]);
        float2 v1 = __half22float2(h2[(size_t)s1 * 64 + lane]);
        float2 v2 = __half22float2(h2[(size_t)s2 * 64 + lane]);
        float2 v3 = __half22float2(h2[(size_t)s3 * 64 + lane]);
        ax += v0.x + v1.x + v2.x + v3.x;
        ay += v0.y + v1.y + v2.y + v3.y;
    }
    for (; i < deg; ++i) {
        int s = sp[i];
        float2 v = __half22float2(h2[(size_t)s * 64 + lane]);
        ax += v.x; ay += v.y;
    }

    float nd = norm_dst[node];
    float2 bb = ((const float2*)bias)[lane];
    float2 o;
    o.x = fmaxf(fmaf(ax, nd, bb.x), 0.f);
    o.y = fmaxf(fmaf(ay, nd, bb.y), 0.f);
    ((float2*)out)[(size_t)node * 64 + lane] = o;
}

extern "C" void kernel_launch(void* const* d_in, const int* in_sizes, int n_in,
                              void* d_out, int out_size, void* d_ws, size_t ws_size,
                              hipStream_t stream) {
    const float* x   = (const float*)d_in[0];
    const float* W1  = (const float*)d_in[1];
    const float* b1  = (const float*)d_in[2];
    const float* W2  = (const float*)d_in[3];
    const float* b2  = (const float*)d_in[4];
    const int*   src = (const int*)d_in[5];
    const int*   dst = (const int*)d_in[6];

    const int N = in_sizes[0] / HD;
    const int E = in_sizes[5];
    float* out = (float*)d_out;

    const int nbA = (N + 255) / 256;

    // workspace layout (zero-needed region contiguous: outdeg, cnt, cursor)
    float*        outdeg  = (float*)d_ws;                 // N   -> norm_src
    unsigned int* cnt     = (unsigned int*)(outdeg + N);  // N
    unsigned int* cursor  = cnt + N;                      // N
    float*        normd   = (float*)(cursor + N);         // N
    unsigned int* offsets = (unsigned int*)(normd + N);   // N
    unsigned int* bsum    = offsets + N;                  // 1024
    unsigned int* boff    = bsum + 1024;                  // 1024
    int*          sorted  = (int*)(boff + 1024);          // E
    __half*       h       = (__half*)(sorted + E);        // N*HD fp16

    // ---- CSR build (shared by both layers) ----
    hipMemsetAsync(outdeg, 0, (size_t)3 * N * 4, stream);
    count_deg<<<(E + 255) / 256, 256, 0, stream>>>(src, dst, outdeg, cnt, E);
    make_norms<<<nbA, 256, 0, stream>>>(outdeg, cnt, normd, N);
    scan_a<<<nbA, 256, 0, stream>>>(cnt, offsets, bsum, N);
    scan_b<<<1, 1024, 0, stream>>>(bsum, boff, nbA);
    scan_c<<<nbA, 256, 0, stream>>>(offsets, boff, N);
    fill_csr<<<(E + 255) / 256, 256, 0, stream>>>(src, dst, offsets, cursor, sorted, E);

    // ---- layer 1 ----
    gemm_norm<<<(N + 31) / 32, 256, 0, stream>>>(x, outdeg, W1, h, N);
    aggregate<<<(N + 3) / 4, 256, 0, stream>>>(h, sorted, offsets, cnt, normd, b1, out, N);

    // ---- layer 2 ----
    gemm_norm<<<(N + 31) / 32, 256, 0, stream>>>(out, outdeg, W2, h, N);
    aggregate<<<(N + 3) / 4, 256, 0, stream>>>(h, sorted, offsets, cnt, normd, b2, out, N);
}